// Round 1
// baseline (208.904 us; speedup 1.0000x reference)
//
#include <hip/hip_runtime.h>

// ============================================================================
// Compile-time real-basis Wigner 3j — mirrors the reference _su2_cg/_q/_w3j
// exactly (double precision at compile time, cast to float for use).
// ============================================================================

__host__ __device__ constexpr double cfact(int n) {
    double r = 1.0;
    for (int i = 2; i <= n; ++i) r *= (double)i;
    return r;
}

__host__ __device__ constexpr double csqrt(double x) {
    if (x <= 0.0) return 0.0;
    double r = x < 1.0 ? 1.0 : x;
    for (int i = 0; i < 80; ++i) r = 0.5 * (r + x / r);
    return r;
}

__host__ __device__ constexpr double su2_cg_elem(int j1, int j2, int j3, int m1, int m2) {
    int m3 = m1 + m2;
    if (m3 < -j3 || m3 > j3) return 0.0;
    double pref = csqrt((double)(2 * j3 + 1) * cfact(j3 + j1 - j2) * cfact(j3 - j1 + j2) *
                        cfact(j1 + j2 - j3) / cfact(j1 + j2 + j3 + 1));
    pref *= csqrt(cfact(j3 + m3) * cfact(j3 - m3) * cfact(j1 - m1) * cfact(j1 + m1) *
                  cfact(j2 - m2) * cfact(j2 + m2));
    double s = 0.0;
    for (int k = 0; k <= j1 + j2 - j3; ++k) {
        int t0 = k, t1 = j1 + j2 - j3 - k, t2 = j1 - m1 - k;
        int t3 = j2 + m2 - k, t4 = j3 - j2 + m1 + k, t5 = j3 - j1 - m2 + k;
        if (t0 < 0 || t1 < 0 || t2 < 0 || t3 < 0 || t4 < 0 || t5 < 0) continue;
        double term = 1.0 / (cfact(t0) * cfact(t1) * cfact(t2) * cfact(t3) * cfact(t4) * cfact(t5));
        s += (k & 1) ? -term : term;
    }
    return pref * s;
}

struct QM { double re[5][5]; double im[5][5]; };

__host__ __device__ constexpr QM qmat(int l) {
    QM q{};
    const double inv2 = 1.0 / csqrt(2.0);
    for (int m = -l; m < 0; ++m) {
        q.re[l + m][l - m] = inv2;    // q[l+m, l+|m|] = 1/sqrt2
        q.im[l + m][l + m] = -inv2;   // q[l+m, l-|m|] = -1j/sqrt2
    }
    q.re[l][l] = 1.0;
    for (int m = 1; m <= l; ++m) {
        double s = (m & 1) ? -1.0 : 1.0;
        q.re[l + m][l + m] = s * inv2;   // (-1)^m/sqrt2
        q.im[l + m][l - m] = s * inv2;   // 1j*(-1)^m/sqrt2
    }
    // phase (-1j)^l
    double pr = 1.0, pi = 0.0;
    switch (l & 3) {
        case 1: pr = 0.0; pi = -1.0; break;
        case 2: pr = -1.0; pi = 0.0; break;
        case 3: pr = 0.0; pi = 1.0; break;
        default: break;
    }
    for (int a = 0; a < 5; ++a)
        for (int b = 0; b < 5; ++b) {
            double re = q.re[a][b], im = q.im[a][b];
            q.re[a][b] = re * pr - im * pi;
            q.im[a][b] = re * pi + im * pr;
        }
    return q;
}

struct W3 { double w[5][5][5]; };

// w3j[j,l,n] = Re( sum_{i,k,m} q1[i,j] q2[k,l] conj(q3[m,n]) * C[i,k,m] )
// with C = su2_cg / sqrt(2*l3+1); C[i,k,m] nonzero only at m = (i-l1)+(k-l2)+l3.
__host__ __device__ constexpr W3 make_w3j(int l1, int l2, int l3) {
    W3 o{};
    const int n1 = 2 * l1 + 1, n2 = 2 * l2 + 1, n3 = 2 * l3 + 1;
    double C[5][5]{};
    const double inv = 1.0 / csqrt((double)(2 * l3 + 1));
    for (int i = 0; i < n1; ++i)
        for (int k = 0; k < n2; ++k)
            C[i][k] = su2_cg_elem(l1, l2, l3, i - l1, k - l2) * inv;
    const QM q1 = qmat(l1), q2 = qmat(l2), q3 = qmat(l3);
    for (int j = 0; j < n1; ++j)
        for (int l = 0; l < n2; ++l)
            for (int n = 0; n < n3; ++n) {
                double s = 0.0;
                for (int i = 0; i < n1; ++i)
                    for (int k = 0; k < n2; ++k) {
                        int m = (i - l1) + (k - l2) + l3;
                        if (m < 0 || m >= n3) continue;
                        double cg = C[i][k];
                        if (cg == 0.0) continue;
                        double r1 = q1.re[i][j], i1 = q1.im[i][j];
                        double r2 = q2.re[k][l], i2 = q2.im[k][l];
                        double zr = r1 * r2 - i1 * i2, zi = r1 * i2 + i1 * r2;
                        // * conj(q3[m][n]), real part
                        s += cg * (zr * q3.re[m][n] + zi * q3.im[m][n]);
                    }
                o.w[j][l][n] = s;
            }
    return o;
}

// One instruction (path): o[n] = wk * sum_{i,k} (alpha*w3j[i,k,n]) * a[i]*b[k]
// alpha = sqrt(2*L3+1) (fan_in == 1 for every output here).
template <int L1, int L2, int L3>
__device__ __forceinline__ void tp_path(float wk, const float* a, const float* b, float* o) {
    constexpr W3 W = make_w3j(L1, L2, L3);
    constexpr double AL = csqrt(2.0 * L3 + 1.0);
#pragma unroll
    for (int n = 0; n < 2 * L3 + 1; ++n) {
        float s = 0.0f;
#pragma unroll
        for (int i = 0; i < 2 * L1 + 1; ++i) {
#pragma unroll
            for (int k = 0; k < 2 * L2 + 1; ++k) {
                const double cw = W.w[i][k][n] * AL;   // constant after unroll
                if (cw != 0.0) s += (float)cw * (a[i] * b[k]);
            }
        }
        o[n] = wk * s;
    }
}

// ============================================================================
// Kernel: one thread per (edge, u-channel). wave = one edge, lane = u (0..63).
// Layouts (per edge):
//   x1[576]  = [u]_l0 (64) | [u*3+m]_l1 (192, off 64) | [u*5+m]_l2 (320, off 256)
//   x2[9]    = b0 | b1[3] | b2[5]
//   w[960]   = 15 instructions x 64 (w[k*64+u])
//   out[3264]= k0..2: off {0,64,128} scalar; k3..8: off 192+192*(k-3), u*3+m;
//              k9..14: off 1344+320*(k-9), u*5+m
// ============================================================================

__global__ __launch_bounds__(256) void dtp_kernel(const float* __restrict__ X1,
                                                  const float* __restrict__ X2,
                                                  const float* __restrict__ WT,
                                                  float* __restrict__ OUT, int E) {
    long idx = (long)blockIdx.x * blockDim.x + threadIdx.x;
    if (idx >= (long)E * 64) return;
    long e = idx >> 6;
    int u = (int)(idx & 63);

    const float* p1 = X1 + e * 576;
    const float* p2 = X2 + e * 9;
    const float* pw = WT + e * 960;
    float* po = OUT + e * 3264;

    float a0 = p1[u];
    float a1[3], a2[5];
#pragma unroll
    for (int m = 0; m < 3; ++m) a1[m] = p1[64 + u * 3 + m];
#pragma unroll
    for (int m = 0; m < 5; ++m) a2[m] = p1[256 + u * 5 + m];

    float b0 = p2[0];
    float b1[3], b2[5];
#pragma unroll
    for (int m = 0; m < 3; ++m) b1[m] = p2[1 + m];
#pragma unroll
    for (int m = 0; m < 5; ++m) b2[m] = p2[4 + m];

    float wk[15];
#pragma unroll
    for (int k = 0; k < 15; ++k) wk[k] = pw[k * 64 + u];

    float A0[1] = {a0}, B0[1] = {b0};
    float t1[1], t3[3], t5[5];

    // ---- l3 = 0 outputs (scalar, coalesced) ----
    tp_path<0, 0, 0>(wk[0], A0, B0, t1);  po[0 + u] = t1[0];     // k=0  (i0,j0)
    tp_path<1, 1, 0>(wk[1], a1, b1, t1);  po[64 + u] = t1[0];    // k=1  (i1,j1)
    tp_path<2, 2, 0>(wk[2], a2, b2, t1);  po[128 + u] = t1[0];   // k=2  (i2,j2)

    // ---- l3 = 1 outputs (3 each, lane-contiguous u*3+m) ----
    tp_path<0, 1, 1>(wk[3], A0, b1, t3);                          // k=3  (i0,j1)
#pragma unroll
    for (int m = 0; m < 3; ++m) po[192 + u * 3 + m] = t3[m];
    tp_path<1, 0, 1>(wk[4], a1, B0, t3);                          // k=4  (i1,j0)
#pragma unroll
    for (int m = 0; m < 3; ++m) po[384 + u * 3 + m] = t3[m];
    tp_path<1, 2, 1>(wk[5], a1, b2, t3);                          // k=5  (i1,j2)
#pragma unroll
    for (int m = 0; m < 3; ++m) po[576 + u * 3 + m] = t3[m];
    tp_path<2, 1, 1>(wk[6], a2, b1, t3);                          // k=6  (i2,j1)
#pragma unroll
    for (int m = 0; m < 3; ++m) po[768 + u * 3 + m] = t3[m];
    tp_path<1, 1, 1>(wk[7], a1, b1, t3);                          // k=7  (i1,j1)
#pragma unroll
    for (int m = 0; m < 3; ++m) po[960 + u * 3 + m] = t3[m];
    tp_path<2, 2, 1>(wk[8], a2, b2, t3);                          // k=8  (i2,j2)
#pragma unroll
    for (int m = 0; m < 3; ++m) po[1152 + u * 3 + m] = t3[m];

    // ---- l3 = 2 outputs (5 each, lane-contiguous u*5+m) ----
    tp_path<0, 2, 2>(wk[9], A0, b2, t5);                          // k=9  (i0,j2)
#pragma unroll
    for (int m = 0; m < 5; ++m) po[1344 + u * 5 + m] = t5[m];
    tp_path<1, 1, 2>(wk[10], a1, b1, t5);                         // k=10 (i1,j1)
#pragma unroll
    for (int m = 0; m < 5; ++m) po[1664 + u * 5 + m] = t5[m];
    tp_path<2, 0, 2>(wk[11], a2, B0, t5);                         // k=11 (i2,j0)
#pragma unroll
    for (int m = 0; m < 5; ++m) po[1984 + u * 5 + m] = t5[m];
    tp_path<2, 2, 2>(wk[12], a2, b2, t5);                         // k=12 (i2,j2)
#pragma unroll
    for (int m = 0; m < 5; ++m) po[2304 + u * 5 + m] = t5[m];
    tp_path<1, 2, 2>(wk[13], a1, b2, t5);                         // k=13 (i1,j2)
#pragma unroll
    for (int m = 0; m < 5; ++m) po[2624 + u * 5 + m] = t5[m];
    tp_path<2, 1, 2>(wk[14], a2, b1, t5);                         // k=14 (i2,j1)
#pragma unroll
    for (int m = 0; m < 5; ++m) po[2944 + u * 5 + m] = t5[m];
}

extern "C" void kernel_launch(void* const* d_in, const int* in_sizes, int n_in,
                              void* d_out, int out_size, void* d_ws, size_t ws_size,
                              hipStream_t stream) {
    (void)n_in; (void)out_size; (void)d_ws; (void)ws_size;
    const float* x1 = (const float*)d_in[0];
    const float* x2 = (const float*)d_in[1];
    const float* wt = (const float*)d_in[2];
    float* out = (float*)d_out;

    int E = in_sizes[0] / 576;
    long total = (long)E * 64;
    int blocks = (int)((total + 255) / 256);
    dtp_kernel<<<blocks, 256, 0, stream>>>(x1, x2, wt, out, E);
}